// Round 8
// baseline (161.950 us; speedup 1.0000x reference)
//
#include <hip/hip_runtime.h>
#include <math.h>

// CapsuleLayer: u = x@W via split-precision f16 MFMA (xh@Wh + xl@Wh + xh@Wl),
// 32x32x16. R18: permlane ABANDONED (R15 + R16/17 both NaN with different
// register-distinctness strategies -> my v_permlane32_swap_b32 semantic model
// is wrong, and it's not unit-testable in this harness; ERRATA recorded).
// R18 = R14 proven base + ONLY the numerically-inert K-loop changes from R15:
//  - A-frag hi ping-pong register prefetch one kt ahead (same LDS reads, one
//    kt earlier -> removes ~120-150cy lgkm stall per kt if exposed).
//  - MFMA issue interleaved acc0/acc1 (dep distance 1 -> 2); per-accumulator
//    term order (h*bh, l*bh, h*bl) unchanged -> bitwise identical.
// Epilogue: R14's exact paired routing with __shfl_xor (proven).
// Proven invariants: never runtime-index acc[] (R6 spill); lane-bit-5 cross
// only via bpermute (R5); C/D layout row=(reg&3)+8*(reg>>2)+4*q, col=ln.
//
// x: [32768,512] fp32  W: [512,512] fp32  v: [32768,32] fp32
// prep_w: W[k][n] -> Wh/Wl tiled [kt][n][k%16] f16 in d_ws (1 MB).
// Main: block = 256 thr (4 waves), tile 64 rows x 512 cols, grid 512
// (2 blocks/CU: LDS 66.56KB, VGPR+ACC<=256 via __launch_bounds__(256,2)).

#define BATCH   32768
#define KDIM    512
#define NDIM    512
#define OUT_DIM 32
#define EPS_F   1e-8f
#define NKT     32            // K tiles of 16
#define KPS     8             // kt per superblock
#define NSB     4             // superblocks

typedef _Float16 half8  __attribute__((ext_vector_type(8)));
typedef _Float16 half4t __attribute__((ext_vector_type(4)));
typedef float   floatx4 __attribute__((ext_vector_type(4)));
typedef float  floatx16 __attribute__((ext_vector_type(16)));

// ---- cross-lane helpers (R7, proven) ----
template <int CTRL>
__device__ __forceinline__ float dpp_mov(float x) {
    return __int_as_float(__builtin_amdgcn_mov_dpp(__float_as_int(x), CTRL, 0xF, 0xF, true));
}
template <int XMASK>   // XMASK <= 31: ds_swizzle BitMode xor (within 32-lane group)
__device__ __forceinline__ float swz_xor(float x) {
    return __int_as_float(__builtin_amdgcn_ds_swizzle(__float_as_int(x), (XMASK << 10) | 31));
}
#define ROR4  0x124
#define ROR8  0x128
#define QXOR1 0xB1
#define QXOR2 0x4E

__device__ __forceinline__ float cap_sum(float x) {
    x += dpp_mov<ROR4>(x);
    x += dpp_mov<ROR8>(x);
    x += swz_xor<16>(x);
    x += __shfl_xor(x, 32);          // lane bit 5: bpermute only
    return x;
}
__device__ __forceinline__ float cap_max(float x) {
    x = fmaxf(x, dpp_mov<ROR4>(x));
    x = fmaxf(x, dpp_mov<ROR8>(x));
    x = fmaxf(x, swz_xor<16>(x));
    x = fmaxf(x, __shfl_xor(x, 32));
    return x;
}
__device__ __forceinline__ float dg_sum(float x) {
    x += dpp_mov<QXOR1>(x);
    x += dpp_mov<QXOR2>(x);
    return x;
}

// ---- prep: W[k][n] fp32 -> Wh/Wl [kt][n][k%16] f16 hi/lo split ----
__global__ void prep_w(const float* __restrict__ W, _Float16* __restrict__ Wh,
                       _Float16* __restrict__ Wl) {
    __shared__ float tile[32][33];
    const int tx = threadIdx.x, ty = threadIdx.y;      // block (32, 8)
    const int n0 = blockIdx.x * 32, k0 = blockIdx.y * 32;
#pragma unroll
    for (int i = 0; i < 4; ++i)
        tile[ty + 8 * i][tx] = W[(size_t)(k0 + ty + 8 * i) * NDIM + n0 + tx];
    __syncthreads();
#pragma unroll
    for (int i = 0; i < 4; ++i) {
        const int k = k0 + tx, n = n0 + ty + 8 * i;
        const float v = tile[tx][ty + 8 * i];          // = W[k][n]
        const _Float16 h = (_Float16)v;
        const _Float16 l = (_Float16)(v - (float)h);
        const size_t off = (size_t)(k >> 4) * (NDIM * 16) + (size_t)n * 16 + (k & 15);
        Wh[off] = h;
        Wl[off] = l;
    }
}

__global__ __launch_bounds__(256, 2)
void capsule_mfma(const float* __restrict__ x, const _Float16* __restrict__ Wh,
                  const _Float16* __restrict__ Wl, float* __restrict__ out) {
    // As[buf(2)][kt'(8)][row 64][64B] = 64 KB, unioned with u_lds[32][520] (66.56 KB)
    __shared__ __align__(16) char smem[66560];
    float (*u_lds)[520] = (float (*)[520])smem;

    const int tid  = threadIdx.x;
    const int w    = tid >> 6;          // wave 0..3
    const int lane = tid & 63;
    const int ln = lane & 31, q = lane >> 5;
    const int rowBlk = blockIdx.x * 64;
    const int C0 = w * 128;

    floatx16 acc[2][4];
#pragma unroll
    for (int mf = 0; mf < 2; ++mf)
#pragma unroll
        for (int nt = 0; nt < 4; ++nt)
#pragma unroll
            for (int i = 0; i < 16; ++i) acc[mf][nt][i] = 0.f;

    // ---- A staging mapping: thread -> (row srow0+8i, kt' skt, quarter skq) ----
    const int srow0 = tid >> 5;          // 0..7
    const int sf    = tid & 31;
    const int skt   = sf >> 2;           // 0..7
    const int skq   = sf & 3;
    const float* aga = x + (size_t)(rowBlk + srow0) * KDIM + skt * 16 + skq * 4;
    const int ssw = (srow0 >> 1) & 3;    // i-invariant ((+8i)>>1 adds 4, &3 unchanged)
    const int woffh = skt * 4096 + srow0 * 64 + (((skq >> 1) ^ ssw) * 16) + (skq & 1) * 8;
    // l-chunk offset = woffh ^ 32

    // ---- A frag read offsets: ar = mf*32+ln; hoff1 = hoff0 + 2048; loff = hoff^32
    const int hoff0 = ln * 64 + ((q ^ ((ln >> 1) & 3)) * 16);

    // ---- B lane offset (halfs): frag (kt,nt) at Wh + kt*8192 + nt*512 + boff
    const int boff = (C0 + ln) * 16 + q * 8;

    // ---- prologue: stage slice 0 -> buf0; load B(0,0) ----
    {
        floatx4 s0[8];
#pragma unroll
        for (int i = 0; i < 8; ++i)
            s0[i] = *(const floatx4*)(aga + (size_t)(8 * i) * KDIM);
#pragma unroll
        for (int i = 0; i < 8; ++i) {
            half4t h4, l4;
#pragma unroll
            for (int j = 0; j < 4; ++j) {
                h4[j] = (_Float16)s0[i][j];
                l4[j] = (_Float16)(s0[i][j] - (float)h4[j]);
            }
            *(half4t*)(smem + woffh + i * 512)        = h4;
            *(half4t*)(smem + (woffh ^ 32) + i * 512) = l4;
        }
    }
    half8 bh[2], bl[2];
    bh[0] = *(const half8*)(Wh + boff);
    bl[0] = *(const half8*)(Wl + boff);

// AC0/AC1: current kt hi-frags (prefetched). AN0/AN1: next-kt hi-frag regs
// (written only when kk < KPS-1). lo-frags read at kk top (needed at MFMA
// slot 3 -> ~2 MFMA issue of cover). Per-acc term order h*bh, l*bh, h*bl
// (identical to R14); acc0/acc1 interleaved for dep distance 2.
#define COMPUTE_KK(kk, AC0, AC1, AN0, AN1)                                      \
    {                                                                           \
        const int kt = s * KPS + (kk);                                          \
        const char* ab = smem + abuf + (kk) * 4096;                             \
        const half8 al0 = *(const half8*)(ab + (hoff0 ^ 32));                   \
        const half8 al1 = *(const half8*)(ab + ((hoff0 + 2048) ^ 32));          \
        if ((kk) < KPS - 1) {                                                   \
            const char* abn = smem + abuf + ((kk) + 1) * 4096;                  \
            AN0 = *(const half8*)(abn + hoff0);                                 \
            AN1 = *(const half8*)(abn + hoff0 + 2048);                          \
        }                                                                       \
        _Pragma("unroll")                                                       \
        for (int nt = 0; nt < 4; ++nt) {                                        \
            const int cu = nt & 1, nx = cu ^ 1;                                 \
            const int kn = (nt < 3) ? kt : ((kt + 1 < NKT) ? kt + 1 : kt);      \
            const int nn = (nt < 3) ? nt + 1 : 0;                               \
            bh[nx] = *(const half8*)(Wh + (size_t)kn * 8192 + nn * 512 + boff); \
            bl[nx] = *(const half8*)(Wl + (size_t)kn * 8192 + nn * 512 + boff); \
            acc[0][nt] = __builtin_amdgcn_mfma_f32_32x32x16_f16(AC0, bh[cu], acc[0][nt], 0, 0, 0); \
            acc[1][nt] = __builtin_amdgcn_mfma_f32_32x32x16_f16(AC1, bh[cu], acc[1][nt], 0, 0, 0); \
            acc[0][nt] = __builtin_amdgcn_mfma_f32_32x32x16_f16(al0, bh[cu], acc[0][nt], 0, 0, 0); \
            acc[1][nt] = __builtin_amdgcn_mfma_f32_32x32x16_f16(al1, bh[cu], acc[1][nt], 0, 0, 0); \
            acc[0][nt] = __builtin_amdgcn_mfma_f32_32x32x16_f16(AC0, bl[cu], acc[0][nt], 0, 0, 0); \
            acc[1][nt] = __builtin_amdgcn_mfma_f32_32x32x16_f16(AC1, bl[cu], acc[1][nt], 0, 0, 0); \
        }                                                                       \
    }

#define STAGE_HALF(h0)                                                          \
    {                                                                           \
        half4t h4, l4;                                                          \
        _Pragma("unroll")                                                       \
        for (int i = 0; i < 4; ++i) {                                           \
            _Pragma("unroll")                                                   \
            for (int j = 0; j < 4; ++j) {                                       \
                h4[j] = (_Float16)sv[i][j];                                     \
                l4[j] = (_Float16)(sv[i][j] - (float)h4[j]);                    \
            }                                                                   \
            *(half4t*)(smem + nbuf + woffh + ((h0) + i) * 512)        = h4;     \
            *(half4t*)(smem + nbuf + ((woffh ^ 32)) + ((h0) + i) * 512) = l4;   \
        }                                                                       \
    }

#pragma unroll 1
    for (int s = 0; s < NSB; ++s) {
        __syncthreads();               // stage(slice s) visible; buf^1 readers done
        const int abuf = (s & 1) * 32768;
        const int nbuf = abuf ^ 32768;
        half8 pa0, pa1, pb0, pb1;      // A hi-frag ping-pong
        {
            const char* ab0 = smem + abuf;
            pa0 = *(const half8*)(ab0 + hoff0);
            pa1 = *(const half8*)(ab0 + hoff0 + 2048);
        }
        floatx4 sv[4];
        if (s + 1 < NSB) {             // load half 0 of slice s+1 (rows +0..+24)
#pragma unroll
            for (int i = 0; i < 4; ++i)
                sv[i] = *(const floatx4*)(aga + (size_t)(s + 1) * 128 + (size_t)(8 * i) * KDIM);
        }
        COMPUTE_KK(0, pa0, pa1, pb0, pb1)
        COMPUTE_KK(1, pb0, pb1, pa0, pa1)
        if (s + 1 < NSB) STAGE_HALF(0)
        if (s + 1 < NSB) {             // load half 1 (rows +32..+56)
#pragma unroll
            for (int i = 0; i < 4; ++i)
                sv[i] = *(const floatx4*)(aga + (size_t)(s + 1) * 128 + (size_t)(8 * (i + 4)) * KDIM);
        }
        COMPUTE_KK(2, pa0, pa1, pb0, pb1)
        COMPUTE_KK(3, pb0, pb1, pa0, pa1)
        COMPUTE_KK(4, pa0, pa1, pb0, pb1)
        COMPUTE_KK(5, pb0, pb1, pa0, pa1)
        if (s + 1 < NSB) STAGE_HALF(4)
        COMPUTE_KK(6, pa0, pa1, pb0, pb1)
        COMPUTE_KK(7, pb0, pb1, pa0, pa1)   // no prefetch write (kk==KPS-1)
    }

    // ---- epilogue: two 32-row phases; acc -> u_lds fp32, then PAIRED routing ----
    // C/D layout 32x32: col = ln, row = (reg&3) + 8*(reg>>2) + 4*q
    const int dgrp = lane & 3;
#pragma unroll
    for (int p = 0; p < 2; ++p) {
        __syncthreads();               // K-loop / previous-phase LDS reads done
        {
            const int mf = p;          // compile-time (p unrolled) — R6 rule
#pragma unroll
            for (int nt = 0; nt < 4; ++nt)
#pragma unroll
                for (int reg = 0; reg < 16; ++reg)
                    u_lds[(reg & 3) + 8 * (reg >> 2) + 4 * q][C0 + nt * 32 + ln] = acc[mf][nt][reg];
        }
        __syncthreads();
        // rows in pairs — two independent chains interleaved (R14, proven +3us)
#pragma unroll 1
        for (int pi = 0; pi < 4; ++pi) {
            const int rl0 = w * 8 + 2 * pi;          // local rows rl0, rl0+1
            const floatx4 uaA = *(const floatx4*)&u_lds[rl0][lane * 8];
            const floatx4 ubA = *(const floatx4*)&u_lds[rl0][lane * 8 + 4];
            const floatx4 uaB = *(const floatx4*)&u_lds[rl0 + 1][lane * 8];
            const floatx4 ubB = *(const floatx4*)&u_lds[rl0 + 1][lane * 8 + 4];
            const float uA[8] = {uaA[0], uaA[1], uaA[2], uaA[3],
                                 ubA[0], ubA[1], ubA[2], ubA[3]};
            const float uB[8] = {uaB[0], uaB[1], uaB[2], uaB[3],
                                 ubB[0], ubB[1], ubB[2], ubB[3]};
            float bA = 0.f, bB = 0.f;
            float vA[8], vB[8];
#pragma unroll
            for (int it = 0; it < 3; ++it) {
                float cA, cB;
                if (it == 0) {
                    cA = 1.0f / 16.0f;               // softmax of zeros
                    cB = 1.0f / 16.0f;
                } else {
                    const float mA = cap_max(bA);
                    const float mB = cap_max(bB);
                    const float eA = __expf(bA - mA);
                    const float eB = __expf(bB - mB);
                    const float sAs = cap_sum(eA);
                    const float sBs = cap_sum(eB);
                    cA = eA / sAs;
                    cB = eB / sBs;
                }
                float s8A[8], s8B[8];
#pragma unroll
                for (int j = 0; j < 8; ++j) { s8A[j] = cA * uA[j]; s8B[j] = cB * uB[j]; }
#pragma unroll
                for (int j = 0; j < 8; ++j) { s8A[j] += dpp_mov<ROR4>(s8A[j]); s8B[j] += dpp_mov<ROR4>(s8B[j]); }
#pragma unroll
                for (int j = 0; j < 8; ++j) { s8A[j] += dpp_mov<ROR8>(s8A[j]); s8B[j] += dpp_mov<ROR8>(s8B[j]); }
#pragma unroll
                for (int j = 0; j < 8; ++j) { s8A[j] += swz_xor<16>(s8A[j]); s8B[j] += swz_xor<16>(s8B[j]); }
#pragma unroll
                for (int j = 0; j < 8; ++j) { s8A[j] += __shfl_xor(s8A[j], 32); s8B[j] += __shfl_xor(s8B[j], 32); }
                float nrmA = 0.f, nrmB = 0.f;
#pragma unroll
                for (int j = 0; j < 8; ++j) { nrmA = fmaf(s8A[j], s8A[j], nrmA); nrmB = fmaf(s8B[j], s8B[j], nrmB); }
                nrmA = dg_sum(nrmA);
                nrmB = dg_sum(nrmB);
                const float scaleA = nrmA / ((1.f + nrmA) * (sqrtf(nrmA) + EPS_F));
                const float scaleB = nrmB / ((1.f + nrmB) * (sqrtf(nrmB) + EPS_F));
#pragma unroll
                for (int j = 0; j < 8; ++j) { vA[j] = scaleA * s8A[j]; vB[j] = scaleB * s8B[j]; }
                if (it < 2) {
                    float dotA = 0.f, dotB = 0.f;
#pragma unroll
                    for (int j = 0; j < 8; ++j) { dotA = fmaf(uA[j], vA[j], dotA); dotB = fmaf(uB[j], vB[j], dotB); }
                    dotA = dg_sum(dotA);
                    dotB = dg_sum(dotB);
                    bA += dotA;
                    bB += dotB;
                }
            }
            if (lane < 4) {
                float4* o0 = (float4*)(out + (size_t)(rowBlk + p * 32 + rl0) * OUT_DIM
                                       + dgrp * 8);
                o0[0] = make_float4(vA[0], vA[1], vA[2], vA[3]);
                o0[1] = make_float4(vA[4], vA[5], vA[6], vA[7]);
                float4* o1 = (float4*)(out + (size_t)(rowBlk + p * 32 + rl0 + 1) * OUT_DIM
                                       + dgrp * 8);
                o1[0] = make_float4(vB[0], vB[1], vB[2], vB[3]);
                o1[1] = make_float4(vB[4], vB[5], vB[6], vB[7]);
            }
        }
    }
}

extern "C" void kernel_launch(void* const* d_in, const int* in_sizes, int n_in,
                              void* d_out, int out_size, void* d_ws, size_t ws_size,
                              hipStream_t stream) {
    const float* x = (const float*)d_in[0];   // [32768, 512]
    const float* W = (const float*)d_in[1];   // [512, 512]
    float* out = (float*)d_out;               // [32768, 32]
    _Float16* Wh = (_Float16*)d_ws;           // [32][512][16] f16 tiled
    _Float16* Wl = Wh + (size_t)NDIM * KDIM;

    prep_w<<<dim3(16, 16), dim3(32, 8), 0, stream>>>(W, Wh, Wl);
    capsule_mfma<<<dim3(BATCH / 64), dim3(256), 0, stream>>>(x, Wh, Wl, out);
}

// Round 9
// 155.030 us; speedup vs baseline: 1.0446x; 1.0446x over previous
//
#include <hip/hip_runtime.h>
#include <math.h>

// CapsuleLayer: u = x@W via split-precision f16 MFMA (xh@Wh + xl@Wh + xh@Wl),
// 32x32x16. R19: PREP_W ATTACK. Cross-round ledger shows scored-vs-dispatch
// gap = +71us with split Wh/Wl prep stores (R10/R14) vs +50us with
// interleaved stores (R13/R18) => prep_w costs ~50-70us (2B-granular
// scattered f16 stores, 256 tiny blocks), a third to half the score.
// capsule_mfma is VERBATIM R14 (proven best: 82.7-85.9us dispatches; R18's
// K-loop surgery regressed 30% -> never deviate from R10's K-loop schedule).
// prep_w v2: no LDS / no sync; lane j owns output column n: 16 coalesced
// k-reads (lane-adjacent 4B), two half8 (16B) stores each to Wh & Wl at
// kt*8192 + n*16 (thread-adjacent 32B runs, fully dense). Identical bytes
// => absmax unchanged.
// Proven invariants: never runtime-index acc[] (R6 spill); lane-bit-5 cross
// only via bpermute (R5); C/D layout row=(reg&3)+8*(reg>>2)+4*q, col=ln.
//
// x: [32768,512] fp32  W: [512,512] fp32  v: [32768,32] fp32
// prep_w: W[k][n] -> Wh/Wl tiled [kt][n][k%16] f16 in d_ws (1 MB).
// Main: block = 256 thr (4 waves), tile 64 rows x 512 cols, grid 512
// (2 blocks/CU: LDS 66.56KB, VGPR<=256 via __launch_bounds__(256,2)).

#define BATCH   32768
#define KDIM    512
#define NDIM    512
#define OUT_DIM 32
#define EPS_F   1e-8f
#define NKT     32            // K tiles of 16
#define KPS     8             // kt per superblock
#define NSB     4             // superblocks

typedef _Float16 half8  __attribute__((ext_vector_type(8)));
typedef _Float16 half4t __attribute__((ext_vector_type(4)));
typedef float   floatx4 __attribute__((ext_vector_type(4)));
typedef float  floatx16 __attribute__((ext_vector_type(16)));

// ---- cross-lane helpers (R7, proven) ----
template <int CTRL>
__device__ __forceinline__ float dpp_mov(float x) {
    return __int_as_float(__builtin_amdgcn_mov_dpp(__float_as_int(x), CTRL, 0xF, 0xF, true));
}
template <int XMASK>   // XMASK <= 31: ds_swizzle BitMode xor (within 32-lane group)
__device__ __forceinline__ float swz_xor(float x) {
    return __int_as_float(__builtin_amdgcn_ds_swizzle(__float_as_int(x), (XMASK << 10) | 31));
}
#define ROR4  0x124
#define ROR8  0x128
#define QXOR1 0xB1
#define QXOR2 0x4E

__device__ __forceinline__ float cap_sum(float x) {
    x += dpp_mov<ROR4>(x);
    x += dpp_mov<ROR8>(x);
    x += swz_xor<16>(x);
    x += __shfl_xor(x, 32);          // lane bit 5: bpermute only
    return x;
}
__device__ __forceinline__ float cap_max(float x) {
    x = fmaxf(x, dpp_mov<ROR4>(x));
    x = fmaxf(x, dpp_mov<ROR8>(x));
    x = fmaxf(x, swz_xor<16>(x));
    x = fmaxf(x, __shfl_xor(x, 32));
    return x;
}
__device__ __forceinline__ float dg_sum(float x) {
    x += dpp_mov<QXOR1>(x);
    x += dpp_mov<QXOR2>(x);
    return x;
}

// ---- prep v2: W[k][n] fp32 -> Wh/Wl [kt][n][k%16] f16 hi/lo split ----
// One thread per output column n within one kt: 16 lane-coalesced reads of
// W[k0+k][n] (adjacent lanes -> adjacent n), then 2x half8 (16B) stores to
// Wh and Wl at halfs offset kt*8192 + n*16 (+8). Adjacent threads write
// adjacent 32B runs -> fully dense stores. No LDS, no barrier.
__global__ __launch_bounds__(256)
void prep_w(const float* __restrict__ W, _Float16* __restrict__ Wh,
            _Float16* __restrict__ Wl) {
    const int kt = blockIdx.x;                      // 0..31
    const int n  = blockIdx.y * 256 + threadIdx.x;  // 0..511
    const int k0 = kt * 16;
    const float* src = W + (size_t)k0 * NDIM + n;
    half8 h[2], l[2];
#pragma unroll
    for (int k = 0; k < 16; ++k) {
        const float v = src[(size_t)k * NDIM];
        const _Float16 hh = (_Float16)v;
        h[k >> 3][k & 7] = hh;
        l[k >> 3][k & 7] = (_Float16)(v - (float)hh);
    }
    const size_t off = (size_t)kt * 8192 + (size_t)n * 16;
    *(half8*)(Wh + off)     = h[0];
    *(half8*)(Wh + off + 8) = h[1];
    *(half8*)(Wl + off)     = l[0];
    *(half8*)(Wl + off + 8) = l[1];
}

__global__ __launch_bounds__(256, 2)
void capsule_mfma(const float* __restrict__ x, const _Float16* __restrict__ Wh,
                  const _Float16* __restrict__ Wl, float* __restrict__ out) {
    // As[buf(2)][kt'(8)][row 64][64B] = 64 KB, unioned with u_lds[32][520] (66.56 KB)
    __shared__ __align__(16) char smem[66560];
    float (*u_lds)[520] = (float (*)[520])smem;

    const int tid  = threadIdx.x;
    const int w    = tid >> 6;          // wave 0..3
    const int lane = tid & 63;
    const int ln = lane & 31, q = lane >> 5;
    const int rowBlk = blockIdx.x * 64;
    const int C0 = w * 128;

    floatx16 acc[2][4];
#pragma unroll
    for (int mf = 0; mf < 2; ++mf)
#pragma unroll
        for (int nt = 0; nt < 4; ++nt)
#pragma unroll
            for (int i = 0; i < 16; ++i) acc[mf][nt][i] = 0.f;

    // ---- A staging mapping: thread -> (row srow0+8i, kt' skt, quarter skq) ----
    const int srow0 = tid >> 5;          // 0..7
    const int sf    = tid & 31;
    const int skt   = sf >> 2;           // 0..7
    const int skq   = sf & 3;
    const float* aga = x + (size_t)(rowBlk + srow0) * KDIM + skt * 16 + skq * 4;
    const int ssw = (srow0 >> 1) & 3;    // i-invariant ((+8i)>>1 adds 4, &3 unchanged)
    const int woffh = skt * 4096 + srow0 * 64 + (((skq >> 1) ^ ssw) * 16) + (skq & 1) * 8;
    // l-chunk offset = woffh ^ 32

    // ---- A frag read offsets: ar = mf*32+ln; hoff1 = hoff0 + 2048; loff = hoff^32
    const int hoff0 = ln * 64 + ((q ^ ((ln >> 1) & 3)) * 16);

    // ---- B lane offset (halfs): frag (kt,nt) at Wh + kt*8192 + nt*512 + boff
    const int boff = (C0 + ln) * 16 + q * 8;

    // ---- prologue: stage slice 0 -> buf0; load B(0,0) ----
    {
        floatx4 s0[8];
#pragma unroll
        for (int i = 0; i < 8; ++i)
            s0[i] = *(const floatx4*)(aga + (size_t)(8 * i) * KDIM);
#pragma unroll
        for (int i = 0; i < 8; ++i) {
            half4t h4, l4;
#pragma unroll
            for (int j = 0; j < 4; ++j) {
                h4[j] = (_Float16)s0[i][j];
                l4[j] = (_Float16)(s0[i][j] - (float)h4[j]);
            }
            *(half4t*)(smem + woffh + i * 512)        = h4;
            *(half4t*)(smem + (woffh ^ 32) + i * 512) = l4;
        }
    }
    half8 bh[2], bl[2];
    bh[0] = *(const half8*)(Wh + boff);
    bl[0] = *(const half8*)(Wl + boff);

#define COMPUTE_KK(kk)                                                          \
    {                                                                           \
        const int kt = s * KPS + (kk);                                          \
        const char* ab = smem + abuf + (kk) * 4096;                             \
        const half8 ah0 = *(const half8*)(ab + hoff0);                          \
        const half8 al0 = *(const half8*)(ab + (hoff0 ^ 32));                   \
        const half8 ah1 = *(const half8*)(ab + hoff0 + 2048);                   \
        const half8 al1 = *(const half8*)(ab + ((hoff0 + 2048) ^ 32));          \
        _Pragma("unroll")                                                       \
        for (int nt = 0; nt < 4; ++nt) {                                        \
            const int cu = nt & 1, nx = cu ^ 1;                                 \
            const int kn = (nt < 3) ? kt : ((kt + 1 < NKT) ? kt + 1 : kt);      \
            const int nn = (nt < 3) ? nt + 1 : 0;                               \
            bh[nx] = *(const half8*)(Wh + (size_t)kn * 8192 + nn * 512 + boff); \
            bl[nx] = *(const half8*)(Wl + (size_t)kn * 8192 + nn * 512 + boff); \
            acc[0][nt] = __builtin_amdgcn_mfma_f32_32x32x16_f16(ah0, bh[cu], acc[0][nt], 0, 0, 0); \
            acc[0][nt] = __builtin_amdgcn_mfma_f32_32x32x16_f16(al0, bh[cu], acc[0][nt], 0, 0, 0); \
            acc[0][nt] = __builtin_amdgcn_mfma_f32_32x32x16_f16(ah0, bl[cu], acc[0][nt], 0, 0, 0); \
            acc[1][nt] = __builtin_amdgcn_mfma_f32_32x32x16_f16(ah1, bh[cu], acc[1][nt], 0, 0, 0); \
            acc[1][nt] = __builtin_amdgcn_mfma_f32_32x32x16_f16(al1, bh[cu], acc[1][nt], 0, 0, 0); \
            acc[1][nt] = __builtin_amdgcn_mfma_f32_32x32x16_f16(ah1, bl[cu], acc[1][nt], 0, 0, 0); \
        }                                                                       \
    }

#define STAGE_HALF(h0)                                                          \
    {                                                                           \
        half4t h4, l4;                                                          \
        _Pragma("unroll")                                                       \
        for (int i = 0; i < 4; ++i) {                                           \
            _Pragma("unroll")                                                   \
            for (int j = 0; j < 4; ++j) {                                       \
                h4[j] = (_Float16)sv[i][j];                                     \
                l4[j] = (_Float16)(sv[i][j] - (float)h4[j]);                    \
            }                                                                   \
            *(half4t*)(smem + nbuf + woffh + ((h0) + i) * 512)        = h4;     \
            *(half4t*)(smem + nbuf + ((woffh ^ 32)) + ((h0) + i) * 512) = l4;   \
        }                                                                       \
    }

#pragma unroll 1
    for (int s = 0; s < NSB; ++s) {
        __syncthreads();               // stage(slice s) visible; buf^1 readers done
        const int abuf = (s & 1) * 32768;
        const int nbuf = abuf ^ 32768;
        floatx4 sv[4];
        if (s + 1 < NSB) {             // load half 0 of slice s+1 (rows +0..+24)
#pragma unroll
            for (int i = 0; i < 4; ++i)
                sv[i] = *(const floatx4*)(aga + (size_t)(s + 1) * 128 + (size_t)(8 * i) * KDIM);
        }
        COMPUTE_KK(0)
        COMPUTE_KK(1)
        if (s + 1 < NSB) STAGE_HALF(0)
        if (s + 1 < NSB) {             // load half 1 (rows +32..+56)
#pragma unroll
            for (int i = 0; i < 4; ++i)
                sv[i] = *(const floatx4*)(aga + (size_t)(s + 1) * 128 + (size_t)(8 * (i + 4)) * KDIM);
        }
        COMPUTE_KK(2)
        COMPUTE_KK(3)
        COMPUTE_KK(4)
        COMPUTE_KK(5)
        if (s + 1 < NSB) STAGE_HALF(4)
        COMPUTE_KK(6)
        COMPUTE_KK(7)
    }

    // ---- epilogue: two 32-row phases; acc -> u_lds fp32, then PAIRED routing ----
    // C/D layout 32x32: col = ln, row = (reg&3) + 8*(reg>>2) + 4*q
    const int dgrp = lane & 3;
#pragma unroll
    for (int p = 0; p < 2; ++p) {
        __syncthreads();               // K-loop / previous-phase LDS reads done
        {
            const int mf = p;          // compile-time (p unrolled) — R6 rule
#pragma unroll
            for (int nt = 0; nt < 4; ++nt)
#pragma unroll
                for (int reg = 0; reg < 16; ++reg)
                    u_lds[(reg & 3) + 8 * (reg >> 2) + 4 * q][C0 + nt * 32 + ln] = acc[mf][nt][reg];
        }
        __syncthreads();
        // rows in pairs — two independent chains interleaved (R14, proven +3us)
#pragma unroll 1
        for (int pi = 0; pi < 4; ++pi) {
            const int rl0 = w * 8 + 2 * pi;          // local rows rl0, rl0+1
            const floatx4 uaA = *(const floatx4*)&u_lds[rl0][lane * 8];
            const floatx4 ubA = *(const floatx4*)&u_lds[rl0][lane * 8 + 4];
            const floatx4 uaB = *(const floatx4*)&u_lds[rl0 + 1][lane * 8];
            const floatx4 ubB = *(const floatx4*)&u_lds[rl0 + 1][lane * 8 + 4];
            const float uA[8] = {uaA[0], uaA[1], uaA[2], uaA[3],
                                 ubA[0], ubA[1], ubA[2], ubA[3]};
            const float uB[8] = {uaB[0], uaB[1], uaB[2], uaB[3],
                                 ubB[0], ubB[1], ubB[2], ubB[3]};
            float bA = 0.f, bB = 0.f;
            float vA[8], vB[8];
#pragma unroll
            for (int it = 0; it < 3; ++it) {
                float cA, cB;
                if (it == 0) {
                    cA = 1.0f / 16.0f;               // softmax of zeros
                    cB = 1.0f / 16.0f;
                } else {
                    const float mA = cap_max(bA);
                    const float mB = cap_max(bB);
                    const float eA = __expf(bA - mA);
                    const float eB = __expf(bB - mB);
                    const float sAs = cap_sum(eA);
                    const float sBs = cap_sum(eB);
                    cA = eA / sAs;
                    cB = eB / sBs;
                }
                float s8A[8], s8B[8];
#pragma unroll
                for (int j = 0; j < 8; ++j) { s8A[j] = cA * uA[j]; s8B[j] = cB * uB[j]; }
#pragma unroll
                for (int j = 0; j < 8; ++j) { s8A[j] += dpp_mov<ROR4>(s8A[j]); s8B[j] += dpp_mov<ROR4>(s8B[j]); }
#pragma unroll
                for (int j = 0; j < 8; ++j) { s8A[j] += dpp_mov<ROR8>(s8A[j]); s8B[j] += dpp_mov<ROR8>(s8B[j]); }
#pragma unroll
                for (int j = 0; j < 8; ++j) { s8A[j] += swz_xor<16>(s8A[j]); s8B[j] += swz_xor<16>(s8B[j]); }
#pragma unroll
                for (int j = 0; j < 8; ++j) { s8A[j] += __shfl_xor(s8A[j], 32); s8B[j] += __shfl_xor(s8B[j], 32); }
                float nrmA = 0.f, nrmB = 0.f;
#pragma unroll
                for (int j = 0; j < 8; ++j) { nrmA = fmaf(s8A[j], s8A[j], nrmA); nrmB = fmaf(s8B[j], s8B[j], nrmB); }
                nrmA = dg_sum(nrmA);
                nrmB = dg_sum(nrmB);
                const float scaleA = nrmA / ((1.f + nrmA) * (sqrtf(nrmA) + EPS_F));
                const float scaleB = nrmB / ((1.f + nrmB) * (sqrtf(nrmB) + EPS_F));
#pragma unroll
                for (int j = 0; j < 8; ++j) { vA[j] = scaleA * s8A[j]; vB[j] = scaleB * s8B[j]; }
                if (it < 2) {
                    float dotA = 0.f, dotB = 0.f;
#pragma unroll
                    for (int j = 0; j < 8; ++j) { dotA = fmaf(uA[j], vA[j], dotA); dotB = fmaf(uB[j], vB[j], dotB); }
                    dotA = dg_sum(dotA);
                    dotB = dg_sum(dotB);
                    bA += dotA;
                    bB += dotB;
                }
            }
            if (lane < 4) {
                float4* o0 = (float4*)(out + (size_t)(rowBlk + p * 32 + rl0) * OUT_DIM
                                       + dgrp * 8);
                o0[0] = make_float4(vA[0], vA[1], vA[2], vA[3]);
                o0[1] = make_float4(vA[4], vA[5], vA[6], vA[7]);
                float4* o1 = (float4*)(out + (size_t)(rowBlk + p * 32 + rl0 + 1) * OUT_DIM
                                       + dgrp * 8);
                o1[0] = make_float4(vB[0], vB[1], vB[2], vB[3]);
                o1[1] = make_float4(vB[4], vB[5], vB[6], vB[7]);
            }
        }
    }
}

extern "C" void kernel_launch(void* const* d_in, const int* in_sizes, int n_in,
                              void* d_out, int out_size, void* d_ws, size_t ws_size,
                              hipStream_t stream) {
    const float* x = (const float*)d_in[0];   // [32768, 512]
    const float* W = (const float*)d_in[1];   // [512, 512]
    float* out = (float*)d_out;               // [32768, 32]
    _Float16* Wh = (_Float16*)d_ws;           // [32][512][16] f16 tiled
    _Float16* Wl = Wh + (size_t)NDIM * KDIM;

    prep_w<<<dim3(NKT, 2), dim3(256), 0, stream>>>(W, Wh, Wl);
    capsule_mfma<<<dim3(BATCH / 64), dim3(256), 0, stream>>>(x, Wh, Wl, out);
}